// Round 10
// baseline (140.426 us; speedup 1.0000x reference)
//
#include <hip/hip_runtime.h>
#include <stdint.h>

#define EPSN 1e-9f

typedef __fp16 f16x8 __attribute__((ext_vector_type(8)));
typedef float f32x4 __attribute__((ext_vector_type(4)));

// Wave-level LDS fence (rule #18: sched_barrier after waitcnt).
#define LDS_FENCE()                                        \
  do {                                                     \
    asm volatile("s_waitcnt lgkmcnt(0)" ::: "memory");     \
    __builtin_amdgcn_sched_barrier(0);                     \
  } while (0)

// ---------------------------------------------------------------------------
// ws layout: [0) inv1_1 [4][3072] f32  [12288) inv2_1 [4][3072] f32
//            byte 98304: w1h [4][48][64][256] f16 (6291456 B)
//            byte 6389760: w2h same                (6291456 B)
// fast path needs 12681216 B total.
// ---------------------------------------------------------------------------

__global__ __launch_bounds__(256) void norms1_kernel(
    const float* __restrict__ x1_1, const float* __restrict__ x2_1,
    float* __restrict__ ws) {
  int p = blockIdx.x * 256 + threadIdx.x;     // 24576 total
  const float* src = (p < 12288) ? x1_1 : x2_1;
  int q = (p < 12288) ? p : p - 12288;
  long base = (long)(q / 3072) * 786432 + (q % 3072);
  float ss = 0.f;
#pragma unroll 8
  for (int c = 0; c < 256; ++c) { float v = src[base + (long)c * 3072]; ss += v * v; }
  ws[p] = 1.f / (sqrtf(ss) + EPSN);
}

// ---------------------------------------------------------------------------
// Level 0 v3: ONE BLOCK PER (b, x2-row y); SHUFFLE-FREE inner loop.
// Each lane j loads its own x2 window (lo f4 | mid f4 | hi scalar, clamped)
// so all 9 v-accumulators are lane-local: pure load->FMA, deep ILP.
// Clamped-lane garbage masked by inv2s zero pads in the epilogue.
// ---------------------------------------------------------------------------
__global__ __launch_bounds__(256) void corr0_kernel(
    const float* __restrict__ x1, const float* __restrict__ x2,
    float* __restrict__ out) {
  int bx = blockIdx.x;
  int L = (bx & 7) * 96 + (bx >> 3);          // 768 = 8 * 96 (bijective)
  int y = L % 192, b = L / 192;
  int tid = threadIdx.x;
  int w = tid >> 6, lane = tid & 63;
  int i_lo = (y - 1) / 4; if (i_lo < 0) i_lo = 0;   // valid i range for this y
  int i_hi = (y + 4) / 4; if (i_hi > 47) i_hi = 47;
  int NI = i_hi - i_lo + 1;                   // 1..3

  __shared__ float red[4][34][64];            // 27 acc + 4 sq + 3 s1 slots
  __shared__ float inv2s[264];                // pads [0..3],[260..263] = 0
  __shared__ float inv1s[3][64];

  float acc[3][9];
#pragma unroll
  for (int r = 0; r < 3; ++r)
#pragma unroll
    for (int v = 0; v < 9; ++v) acc[r][v] = 0.f;
  float sq0 = 0.f, sq1 = 0.f, sq2 = 0.f, sq3 = 0.f;
  float s1[3] = {0.f, 0.f, 0.f};

  const float* x2mid = x2 + (long)b * 12582912 + (long)y * 256 + 4 * lane;
  const float* x2lo  = x2mid - ((lane == 0) ? 0 : 4);    // 16B-aligned either way
  const float* x2hi  = x2mid + ((lane == 63) ? 3 : 4);   // col 4j+4 (clamped)
  const float* x1p[3];
#pragma unroll
  for (int r = 0; r < 3; ++r) {
    int ir = i_lo + r; if (ir > 47) ir = 47;  // clamp (discarded if r>=NI)
    x1p[r] = x1 + (long)b * 12582912 + (long)(4 * ir) * 256 + 4 * lane;
  }

#pragma unroll 8
  for (int cc = 0; cc < 64; ++cc) {
    long off = (long)(w * 64 + cc) * 49152;
    float4 fm = *reinterpret_cast<const float4*>(x2mid + off);
    float4 fl = *reinterpret_cast<const float4*>(x2lo + off);
    float fh = x2hi[off];
    sq0 += fm.x * fm.x; sq1 += fm.y * fm.y; sq2 += fm.z * fm.z; sq3 += fm.w * fm.w;
#pragma unroll
    for (int r = 0; r < 3; ++r) {
      float xv = x1p[r][off];
      s1[r] += xv * xv;
      acc[r][0] += xv * fl.x; acc[r][1] += xv * fl.y;
      acc[r][2] += xv * fl.z; acc[r][3] += xv * fl.w;
      acc[r][4] += xv * fm.x; acc[r][5] += xv * fm.y;
      acc[r][6] += xv * fm.z; acc[r][7] += xv * fm.w;
      acc[r][8] += xv * fh;
    }
  }

  // dump to LDS for cross-wave (channel) reduction
#pragma unroll
  for (int r = 0; r < 3; ++r) {
#pragma unroll
    for (int v = 0; v < 9; ++v) red[w][r * 9 + v][lane] = acc[r][v];
    red[w][31 + r][lane] = s1[r];
  }
  red[w][27][lane] = sq0; red[w][28][lane] = sq1;
  red[w][29][lane] = sq2; red[w][30][lane] = sq3;
  __syncthreads();
  {
    int comp = tid & 3, jj = tid >> 2;        // col = tid (0..255)
    float ss = red[0][27 + comp][jj] + red[1][27 + comp][jj] +
               red[2][27 + comp][jj] + red[3][27 + comp][jj];
    inv2s[4 + tid] = 1.f / (sqrtf(ss) + EPSN);
    if (tid < 4) { inv2s[tid] = 0.f; inv2s[260 + tid] = 0.f; }
    if (tid < 192) {
      int r = tid >> 6, j = tid & 63;
      float t = red[0][31 + r][j] + red[1][31 + r][j] +
                red[2][31 + r][j] + red[3][31 + r][j];
      inv1s[r][j] = 1.f / (sqrtf(t) + EPSN);
    }
  }
  __syncthreads();
  int lim = NI * 576;
  for (int idx = tid; idx < lim; idx += 256) {
    int r = idx / 576, rem = idx - r * 576;
    int v = rem >> 6, j = rem & 63;
    int i_r = i_lo + r;
    int u_r = y - 4 * i_r + 4;                // in [0,8]
    float s = red[0][r * 9 + v][j] + red[1][r * 9 + v][j] +
              red[2][r * 9 + v][j] + red[3][r * 9 + v][j];
    out[(long)b * 1741824 + (long)u_r * 27648 + (long)v * 3072 + i_r * 64 + j] =
        s * inv1s[r][j] * inv2s[4 * j + v];   // 4 + (4j+v-4); pads mask OOB
  }
}

// ---------------------------------------------------------------------------
// Zero-fill level-0 outputs with OOB x2 row: (i=0,u=0..3) and (i=47,u=8).
// ---------------------------------------------------------------------------
__global__ __launch_bounds__(256) void zfill0_kernel(float* __restrict__ out) {
  int idx = blockIdx.x * 256 + threadIdx.x;
  int b = idx / 2880, rem = idx - b * 2880;
  int k = rem / 576, rem2 = rem - k * 576;
  int v = rem2 >> 6, j = rem2 & 63;
  int u = (k < 4) ? k : 8;
  int i = (k < 4) ? 0 : 47;
  out[(long)b * 1741824 + (long)u * 27648 + (long)v * 3072 + i * 64 + j] = 0.f;
}

// ---------------------------------------------------------------------------
// Normalize + f16 + transpose level-1 tensors into ws (unchanged, passing).
// ---------------------------------------------------------------------------
__global__ __launch_bounds__(256) void xpose1_kernel(
    const float* __restrict__ x1, const float* __restrict__ x2,
    __fp16* __restrict__ o1, __fp16* __restrict__ o2) {
  int bx = blockIdx.x;                        // 384 = 2 * 4 * 48
  int tz = bx & 1; int rem = bx >> 1;
  int i = rem % 48, b = rem / 48;
  const float* src = tz ? x2 : x1;
  __fp16* dst = (tz ? o2 : o1) + (long)(b * 48 + i) * 16384;  // 64*256
  __shared__ uint32_t lds[64 * 128];          // 64 rows x 512 B
  __shared__ float sred[4][64];
  int t = threadIdx.x;
  int j = t & 63, cg = t >> 6;                // wave = cg
  const float* sp = src + (long)b * 786432 + (long)i * 64 + j;
  float ss = 0.f;
#pragma unroll 8
  for (int c8 = 0; c8 < 64; ++c8) {
    float v = sp[(long)(cg * 64 + c8) * 3072];
    ss += v * v;
  }
  sred[cg][j] = ss;
  __syncthreads();
  float invv = 1.f / (sqrtf(sred[0][j] + sred[1][j] + sred[2][j] + sred[3][j]) + EPSN);
#pragma unroll
  for (int cb = 0; cb < 8; ++cb) {
    uint32_t pk[4];
#pragma unroll
    for (int e2 = 0; e2 < 4; ++e2) {
      int c0 = cg * 64 + cb * 8 + e2 * 2;
      __fp16 h0 = (__fp16)(sp[(long)c0 * 3072] * invv);
      __fp16 h1 = (__fp16)(sp[(long)(c0 + 1) * 3072] * invv);
      pk[e2] = (uint32_t)__builtin_bit_cast(uint16_t, h0) |
               ((uint32_t)__builtin_bit_cast(uint16_t, h1) << 16);
    }
    int byteoff = j * 512 + ((cg * 128 + cb * 16) ^ ((j & 7) << 4));
    *reinterpret_cast<uint4*>(reinterpret_cast<char*>(lds) + byteoff) =
        make_uint4(pk[0], pk[1], pk[2], pk[3]);
  }
  __syncthreads();
#pragma unroll
  for (int rep = 0; rep < 8; ++rep) {
    int idx = rep * 256 + t;
    int jj = idx >> 5, cb = idx & 31;
    int byteoff = jj * 512 + ((cb * 16) ^ ((jj & 7) << 4));
    uint4 val = *reinterpret_cast<const uint4*>(
        reinterpret_cast<const char*>(lds) + byteoff);
    *reinterpret_cast<uint4*>(reinterpret_cast<char*>(dst) + jj * 512 + cb * 16) = val;
  }
}

// ---------------------------------------------------------------------------
// Level 1 via MFMA, zfill merged (unchanged, passing).
// ---------------------------------------------------------------------------
__device__ const int OFFS39[39] = {
    0, 1, -1, 2, -2, 3, -3, 4, -4, 5, -5, 6, -6, 8, -8, 9, -9, 10, -10,
    12, -12, 15, -15, 16, -16, 18, -18, 20, -20, 27, -27, 32, -32, 36, -36,
    48, -48, 64, -64};

__global__ __launch_bounds__(64) void corr1m_kernel(
    const __fp16* __restrict__ w1, const __fp16* __restrict__ w2,
    float* __restrict__ out) {
  const int dils[6] = {1, 2, 3, 5, 9, 16};
  int bx = blockIdx.x;
  int L = (bx & 7) * 936 + (bx >> 3);         // 7488 = 8 * 936 (bijective)
  int oi = L % 39, i = (L / 39) % 48, b = L / 1872;
  int o = OFFS39[oi];
  int y = i + o;
  bool valid = (y >= 0 && y < 48);
  int l = threadIdx.x;
  __shared__ float c_lds[64][65];

  if (valid) {
    int lm = l & 15, lk = l >> 4;
    const __fp16* A = w1 + (long)(b * 48 + i) * 16384;   // [j1][c]
    const __fp16* B = w2 + (long)(b * 48 + y) * 16384;   // [j2][c]
    f32x4 acc[4][4];
#pragma unroll
    for (int tm = 0; tm < 4; ++tm)
#pragma unroll
      for (int tn = 0; tn < 4; ++tn) acc[tm][tn] = (f32x4)0.f;

    for (int ks = 0; ks < 8; ++ks) {
      f16x8 af[4], bf[4];
      int ko = ks * 32 + lk * 8;
#pragma unroll
      for (int tm = 0; tm < 4; ++tm)
        af[tm] = __builtin_bit_cast(f16x8, *reinterpret_cast<const uint4*>(
                     A + (tm * 16 + lm) * 256 + ko));
#pragma unroll
      for (int tn = 0; tn < 4; ++tn)
        bf[tn] = __builtin_bit_cast(f16x8, *reinterpret_cast<const uint4*>(
                     B + (tn * 16 + lm) * 256 + ko));
#pragma unroll
      for (int tm = 0; tm < 4; ++tm)
#pragma unroll
        for (int tn = 0; tn < 4; ++tn)
          acc[tm][tn] = __builtin_amdgcn_mfma_f32_16x16x32_f16(
              af[tm], bf[tn], acc[tm][tn], 0, 0, 0);
    }
#pragma unroll
    for (int tm = 0; tm < 4; ++tm)
#pragma unroll
      for (int tn = 0; tn < 4; ++tn)
#pragma unroll
        for (int r = 0; r < 4; ++r)
          c_lds[tm * 16 + lk * 4 + r][tn * 16 + lm] = acc[tm][tn][r];
    LDS_FENCE();
  }

#pragma unroll
  for (int dI = 0; dI < 6; ++dI) {
    int d = dils[dI];
    if (o % d) continue;
    int ud = o / d;
    if (ud < -4 || ud > 4) continue;
    long ob = (long)b * 1741824 + (long)(1 + dI) * 248832 +
              (long)(ud + 4) * 27648 + (long)i * 64 + l;
#pragma unroll
    for (int v = 0; v < 9; ++v) {
      float val = 0.f;
      if (valid) {
        int j2 = l + (v - 4) * d;
        val = (j2 >= 0 && j2 < 64) ? c_lds[l][j2] : 0.f;
      }
      out[ob + (long)v * 3072] = val;
    }
  }
}

// ---------------------------------------------------------------------------
// Fallback level-1 (round-6 passing kernel) for small ws_size.
// ---------------------------------------------------------------------------
__global__ __launch_bounds__(64) void corr1_kernel(
    const float* __restrict__ x1, const float* __restrict__ x2,
    const float* __restrict__ ws, float* __restrict__ out) {
  int bx = blockIdx.x;
  int L = (bx & 7) * 1296 + (bx >> 3);
  int u = L % 9, dI = (L / 9) % 6, i = (L / 54) % 48, b = L / 2592;
  const int dils[6] = {1, 2, 3, 5, 9, 16};
  int d = dils[dI];
  int y = i + (u - 4) * d;
  int lane = threadIdx.x;
  long ob = (long)b * 1741824 + (long)(1 + dI) * 248832 + (long)u * 27648 +
            (long)i * 64 + lane;
  if (y < 0 || y >= 48) {
#pragma unroll
    for (int v = 0; v < 9; ++v) out[ob + v * 3072] = 0.f;
    return;
  }
  __shared__ uint4 x2t[192];
  x2t[lane] = make_uint4(0, 0, 0, 0);
  x2t[lane + 64] = make_uint4(0, 0, 0, 0);
  x2t[lane + 128] = make_uint4(0, 0, 0, 0);
  float acc[9];
#pragma unroll
  for (int v = 0; v < 9; ++v) acc[v] = 0.f;
  const float* x2row = x2 + (long)b * 786432 + (long)y * 64 + lane;
  const float* x1row = x1 + (long)b * 786432 + (long)i * 64 + lane;
#pragma unroll 1
  for (int cc8 = 0; cc8 < 32; ++cc8) {
    float x1v[8]; uint32_t xb[8];
#pragma unroll
    for (int cc = 0; cc < 8; ++cc) {
      long c = cc8 * 8 + cc;
      xb[cc] = __float_as_uint(x2row[c * 3072]) + 0x8000u;
      x1v[cc] = x1row[c * 3072];
    }
    uint4 pk;
    pk.x = (xb[0] >> 16) | (xb[1] & 0xffff0000u);
    pk.y = (xb[2] >> 16) | (xb[3] & 0xffff0000u);
    pk.z = (xb[4] >> 16) | (xb[5] & 0xffff0000u);
    pk.w = (xb[6] >> 16) | (xb[7] & 0xffff0000u);
    x2t[64 + lane] = pk;
    LDS_FENCE();
#pragma unroll
    for (int v = 0; v < 9; ++v) {
      uint4 q = x2t[64 + lane + (v - 4) * d];
      float s;
      s  = x1v[0] * __uint_as_float(q.x << 16);
      s += x1v[1] * __uint_as_float(q.x & 0xffff0000u);
      s += x1v[2] * __uint_as_float(q.y << 16);
      s += x1v[3] * __uint_as_float(q.y & 0xffff0000u);
      s += x1v[4] * __uint_as_float(q.z << 16);
      s += x1v[5] * __uint_as_float(q.z & 0xffff0000u);
      s += x1v[6] * __uint_as_float(q.w << 16);
      s += x1v[7] * __uint_as_float(q.w & 0xffff0000u);
      acc[v] += s;
    }
    LDS_FENCE();
  }
  const float* i1 = ws + b * 3072 + i * 64;
  const float* i2 = ws + 12288 + b * 3072 + y * 64;
  float inv1 = i1[lane];
#pragma unroll
  for (int v = 0; v < 9; ++v) {
    int col = lane + (v - 4) * d;
    float i2v = (col >= 0 && col < 64) ? i2[col] : 0.f;
    out[ob + v * 3072] = acc[v] * inv1 * i2v;
  }
}

extern "C" void kernel_launch(void* const* d_in, const int* in_sizes, int n_in,
                              void* d_out, int out_size, void* d_ws, size_t ws_size,
                              hipStream_t stream) {
  const float* x1_0 = (const float*)d_in[0];
  const float* x1_1 = (const float*)d_in[1];
  const float* x2_0 = (const float*)d_in[2];
  const float* x2_1 = (const float*)d_in[3];
  float* out = (float*)d_out;
  float* ws = (float*)d_ws;
  corr0_kernel<<<768, 256, 0, stream>>>(x1_0, x2_0, out);
  zfill0_kernel<<<45, 256, 0, stream>>>(out);
  if (ws_size >= 12681216) {
    __fp16* w1h = (__fp16*)((char*)d_ws + 98304);
    __fp16* w2h = w1h + 3145728;              // 4*48*64*256 elems
    xpose1_kernel<<<384, 256, 0, stream>>>(x1_1, x2_1, w1h, w2h);
    corr1m_kernel<<<7488, 64, 0, stream>>>(w1h, w2h, out);
  } else {
    norms1_kernel<<<96, 256, 0, stream>>>(x1_1, x2_1, ws);
    corr1_kernel<<<10368, 64, 0, stream>>>(x1_1, x2_1, ws, out);
  }
}

// Round 11
// 134.512 us; speedup vs baseline: 1.0440x; 1.0440x over previous
//
#include <hip/hip_runtime.h>
#include <stdint.h>

#define EPSN 1e-9f

typedef __fp16 f16x8 __attribute__((ext_vector_type(8)));
typedef float f32x4 __attribute__((ext_vector_type(4)));

// Wave-level LDS fence (rule #18: sched_barrier after waitcnt).
#define LDS_FENCE()                                        \
  do {                                                     \
    asm volatile("s_waitcnt lgkmcnt(0)" ::: "memory");     \
    __builtin_amdgcn_sched_barrier(0);                     \
  } while (0)

// ---------------------------------------------------------------------------
// ws layout: [0) inv1_1 [4][3072] f32  [12288) inv2_1 [4][3072] f32
//            byte 98304: w1h [4][48][64][256] f16 (6291456 B)
//            byte 6389760: w2h same                (6291456 B)
// fast path needs 12681216 B total.
// ---------------------------------------------------------------------------

__global__ __launch_bounds__(256) void norms1_kernel(
    const float* __restrict__ x1_1, const float* __restrict__ x2_1,
    float* __restrict__ ws) {
  int p = blockIdx.x * 256 + threadIdx.x;     // 24576 total
  const float* src = (p < 12288) ? x1_1 : x2_1;
  int q = (p < 12288) ? p : p - 12288;
  long base = (long)(q / 3072) * 786432 + (q % 3072);
  float ss = 0.f;
#pragma unroll 8
  for (int c = 0; c < 256; ++c) { float v = src[base + (long)c * 3072]; ss += v * v; }
  ws[p] = 1.f / (sqrtf(ss) + EPSN);
}

// ---------------------------------------------------------------------------
// Level 0 v4: block per (b, x2-row y); lane-local windows (shuffle-free) +
// MANUAL PING-PONG PIPELINE (chunk=4 channels) so ~4 iterations of loads
// stay in flight per wave (v3 was register-starved at VGPR=52 -> 1.2 TB/s).
// FMA order per accumulator identical to v3.
// ---------------------------------------------------------------------------
__global__ __launch_bounds__(256, 1) void corr0_kernel(
    const float* __restrict__ x1, const float* __restrict__ x2,
    float* __restrict__ out) {
  int bx = blockIdx.x;
  int L = (bx & 7) * 96 + (bx >> 3);          // 768 = 8 * 96 (bijective)
  int y = L % 192, b = L / 192;
  int tid = threadIdx.x;
  int w = tid >> 6, lane = tid & 63;
  int i_lo = (y - 1) / 4; if (i_lo < 0) i_lo = 0;   // valid i range for this y
  int i_hi = (y + 4) / 4; if (i_hi > 47) i_hi = 47;
  int NI = i_hi - i_lo + 1;                   // 1..3

  __shared__ float red[4][34][64];            // 27 acc + 4 sq + 3 s1 slots
  __shared__ float inv2s[264];                // pads [0..3],[260..263] = 0
  __shared__ float inv1s[3][64];

  float acc[3][9];
#pragma unroll
  for (int r = 0; r < 3; ++r)
#pragma unroll
    for (int v = 0; v < 9; ++v) acc[r][v] = 0.f;
  float sq0 = 0.f, sq1 = 0.f, sq2 = 0.f, sq3 = 0.f;
  float s1[3] = {0.f, 0.f, 0.f};

  const float* x2mid = x2 + (long)b * 12582912 + (long)y * 256 + 4 * lane;
  const float* x2lo  = x2mid - ((lane == 0) ? 0 : 4);    // 16B-aligned either way
  const float* x2hi  = x2mid + ((lane == 63) ? 3 : 4);   // col 4j+4 (clamped)
  const float* x1p0, *x1p1, *x1p2;
  {
    int i0 = i_lo, i1c = i_lo + 1, i2c = i_lo + 2;
    if (i1c > 47) i1c = 47;
    if (i2c > 47) i2c = 47;
    x1p0 = x1 + (long)b * 12582912 + (long)(4 * i0) * 256 + 4 * lane;
    x1p1 = x1 + (long)b * 12582912 + (long)(4 * i1c) * 256 + 4 * lane;
    x1p2 = x1 + (long)b * 12582912 + (long)(4 * i2c) * 256 + 4 * lane;
  }

#define LOADCH(FM, FL, FH, X0, X1, X2, BASE)                          \
  do {                                                                \
    _Pragma("unroll")                                                 \
    for (int q = 0; q < 4; ++q) {                                     \
      long off = (long)((BASE) + q) * 49152;                          \
      FM[q] = *reinterpret_cast<const float4*>(x2mid + off);          \
      FL[q] = *reinterpret_cast<const float4*>(x2lo + off);           \
      FH[q] = x2hi[off];                                              \
      X0[q] = x1p0[off];                                              \
      X1[q] = x1p1[off];                                              \
      X2[q] = x1p2[off];                                              \
    }                                                                 \
  } while (0)

#define FMACH(FM, FL, FH, X0, X1, X2)                                 \
  do {                                                                \
    _Pragma("unroll")                                                 \
    for (int q = 0; q < 4; ++q) {                                     \
      float4 fm = FM[q], fl = FL[q]; float fh = FH[q];                \
      sq0 += fm.x * fm.x; sq1 += fm.y * fm.y;                         \
      sq2 += fm.z * fm.z; sq3 += fm.w * fm.w;                         \
      float xv = X0[q];                                               \
      s1[0] += xv * xv;                                               \
      acc[0][0] += xv * fl.x; acc[0][1] += xv * fl.y;                 \
      acc[0][2] += xv * fl.z; acc[0][3] += xv * fl.w;                 \
      acc[0][4] += xv * fm.x; acc[0][5] += xv * fm.y;                 \
      acc[0][6] += xv * fm.z; acc[0][7] += xv * fm.w;                 \
      acc[0][8] += xv * fh;                                           \
      xv = X1[q];                                                     \
      s1[1] += xv * xv;                                               \
      acc[1][0] += xv * fl.x; acc[1][1] += xv * fl.y;                 \
      acc[1][2] += xv * fl.z; acc[1][3] += xv * fl.w;                 \
      acc[1][4] += xv * fm.x; acc[1][5] += xv * fm.y;                 \
      acc[1][6] += xv * fm.z; acc[1][7] += xv * fm.w;                 \
      acc[1][8] += xv * fh;                                           \
      xv = X2[q];                                                     \
      s1[2] += xv * xv;                                               \
      acc[2][0] += xv * fl.x; acc[2][1] += xv * fl.y;                 \
      acc[2][2] += xv * fl.z; acc[2][3] += xv * fl.w;                 \
      acc[2][4] += xv * fm.x; acc[2][5] += xv * fm.y;                 \
      acc[2][6] += xv * fm.z; acc[2][7] += xv * fm.w;                 \
      acc[2][8] += xv * fh;                                           \
    }                                                                 \
  } while (0)

  {
    float4 fmA[4], flA[4]; float fhA[4], x0A[4], x1A[4], x2A[4];
    float4 fmB[4], flB[4]; float fhB[4], x0B[4], x1B[4], x2B[4];
    int base = w * 64;
    LOADCH(fmA, flA, fhA, x0A, x1A, x2A, base);
#pragma unroll 1
    for (int ck = 0; ck < 8; ++ck) {          // 8 pairs x 2 chunks x 4 ch = 64
      int b0 = base + ck * 8;
      LOADCH(fmB, flB, fhB, x0B, x1B, x2B, b0 + 4);
      FMACH(fmA, flA, fhA, x0A, x1A, x2A);
      if (ck < 7) LOADCH(fmA, flA, fhA, x0A, x1A, x2A, b0 + 8);
      FMACH(fmB, flB, fhB, x0B, x1B, x2B);
    }
  }
#undef LOADCH
#undef FMACH

  // dump to LDS for cross-wave (channel) reduction
#pragma unroll
  for (int r = 0; r < 3; ++r) {
#pragma unroll
    for (int v = 0; v < 9; ++v) red[w][r * 9 + v][lane] = acc[r][v];
    red[w][31 + r][lane] = s1[r];
  }
  red[w][27][lane] = sq0; red[w][28][lane] = sq1;
  red[w][29][lane] = sq2; red[w][30][lane] = sq3;
  __syncthreads();
  {
    int comp = tid & 3, jj = tid >> 2;        // col = tid (0..255)
    float ss = red[0][27 + comp][jj] + red[1][27 + comp][jj] +
               red[2][27 + comp][jj] + red[3][27 + comp][jj];
    inv2s[4 + tid] = 1.f / (sqrtf(ss) + EPSN);
    if (tid < 4) { inv2s[tid] = 0.f; inv2s[260 + tid] = 0.f; }
    if (tid < 192) {
      int r = tid >> 6, j = tid & 63;
      float t = red[0][31 + r][j] + red[1][31 + r][j] +
                red[2][31 + r][j] + red[3][31 + r][j];
      inv1s[r][j] = 1.f / (sqrtf(t) + EPSN);
    }
  }
  __syncthreads();
  int lim = NI * 576;
  for (int idx = tid; idx < lim; idx += 256) {
    int r = idx / 576, rem = idx - r * 576;
    int v = rem >> 6, j = rem & 63;
    int i_r = i_lo + r;
    int u_r = y - 4 * i_r + 4;                // in [0,8]
    float s = red[0][r * 9 + v][j] + red[1][r * 9 + v][j] +
              red[2][r * 9 + v][j] + red[3][r * 9 + v][j];
    out[(long)b * 1741824 + (long)u_r * 27648 + (long)v * 3072 + i_r * 64 + j] =
        s * inv1s[r][j] * inv2s[4 * j + v];   // 4 + (4j+v-4); pads mask OOB
  }
}

// ---------------------------------------------------------------------------
// Zero-fill level-0 outputs with OOB x2 row: (i=0,u=0..3) and (i=47,u=8).
// ---------------------------------------------------------------------------
__global__ __launch_bounds__(256) void zfill0_kernel(float* __restrict__ out) {
  int idx = blockIdx.x * 256 + threadIdx.x;
  int b = idx / 2880, rem = idx - b * 2880;
  int k = rem / 576, rem2 = rem - k * 576;
  int v = rem2 >> 6, j = rem2 & 63;
  int u = (k < 4) ? k : 8;
  int i = (k < 4) ? 0 : 47;
  out[(long)b * 1741824 + (long)u * 27648 + (long)v * 3072 + i * 64 + j] = 0.f;
}

// ---------------------------------------------------------------------------
// Normalize + f16 + transpose level-1 tensors into ws (unchanged, passing).
// ---------------------------------------------------------------------------
__global__ __launch_bounds__(256) void xpose1_kernel(
    const float* __restrict__ x1, const float* __restrict__ x2,
    __fp16* __restrict__ o1, __fp16* __restrict__ o2) {
  int bx = blockIdx.x;                        // 384 = 2 * 4 * 48
  int tz = bx & 1; int rem = bx >> 1;
  int i = rem % 48, b = rem / 48;
  const float* src = tz ? x2 : x1;
  __fp16* dst = (tz ? o2 : o1) + (long)(b * 48 + i) * 16384;  // 64*256
  __shared__ uint32_t lds[64 * 128];          // 64 rows x 512 B
  __shared__ float sred[4][64];
  int t = threadIdx.x;
  int j = t & 63, cg = t >> 6;                // wave = cg
  const float* sp = src + (long)b * 786432 + (long)i * 64 + j;
  float ss = 0.f;
#pragma unroll 8
  for (int c8 = 0; c8 < 64; ++c8) {
    float v = sp[(long)(cg * 64 + c8) * 3072];
    ss += v * v;
  }
  sred[cg][j] = ss;
  __syncthreads();
  float invv = 1.f / (sqrtf(sred[0][j] + sred[1][j] + sred[2][j] + sred[3][j]) + EPSN);
#pragma unroll
  for (int cb = 0; cb < 8; ++cb) {
    uint32_t pk[4];
#pragma unroll
    for (int e2 = 0; e2 < 4; ++e2) {
      int c0 = cg * 64 + cb * 8 + e2 * 2;
      __fp16 h0 = (__fp16)(sp[(long)c0 * 3072] * invv);
      __fp16 h1 = (__fp16)(sp[(long)(c0 + 1) * 3072] * invv);
      pk[e2] = (uint32_t)__builtin_bit_cast(uint16_t, h0) |
               ((uint32_t)__builtin_bit_cast(uint16_t, h1) << 16);
    }
    int byteoff = j * 512 + ((cg * 128 + cb * 16) ^ ((j & 7) << 4));
    *reinterpret_cast<uint4*>(reinterpret_cast<char*>(lds) + byteoff) =
        make_uint4(pk[0], pk[1], pk[2], pk[3]);
  }
  __syncthreads();
#pragma unroll
  for (int rep = 0; rep < 8; ++rep) {
    int idx = rep * 256 + t;
    int jj = idx >> 5, cb = idx & 31;
    int byteoff = jj * 512 + ((cb * 16) ^ ((jj & 7) << 4));
    uint4 val = *reinterpret_cast<const uint4*>(
        reinterpret_cast<const char*>(lds) + byteoff);
    *reinterpret_cast<uint4*>(reinterpret_cast<char*>(dst) + jj * 512 + cb * 16) = val;
  }
}

// ---------------------------------------------------------------------------
// Level 1 via MFMA, zfill merged (unchanged, passing).
// ---------------------------------------------------------------------------
__device__ const int OFFS39[39] = {
    0, 1, -1, 2, -2, 3, -3, 4, -4, 5, -5, 6, -6, 8, -8, 9, -9, 10, -10,
    12, -12, 15, -15, 16, -16, 18, -18, 20, -20, 27, -27, 32, -32, 36, -36,
    48, -48, 64, -64};

__global__ __launch_bounds__(64) void corr1m_kernel(
    const __fp16* __restrict__ w1, const __fp16* __restrict__ w2,
    float* __restrict__ out) {
  const int dils[6] = {1, 2, 3, 5, 9, 16};
  int bx = blockIdx.x;
  int L = (bx & 7) * 936 + (bx >> 3);         // 7488 = 8 * 936 (bijective)
  int oi = L % 39, i = (L / 39) % 48, b = L / 1872;
  int o = OFFS39[oi];
  int y = i + o;
  bool valid = (y >= 0 && y < 48);
  int l = threadIdx.x;
  __shared__ float c_lds[64][65];

  if (valid) {
    int lm = l & 15, lk = l >> 4;
    const __fp16* A = w1 + (long)(b * 48 + i) * 16384;   // [j1][c]
    const __fp16* B = w2 + (long)(b * 48 + y) * 16384;   // [j2][c]
    f32x4 acc[4][4];
#pragma unroll
    for (int tm = 0; tm < 4; ++tm)
#pragma unroll
      for (int tn = 0; tn < 4; ++tn) acc[tm][tn] = (f32x4)0.f;

    for (int ks = 0; ks < 8; ++ks) {
      f16x8 af[4], bf[4];
      int ko = ks * 32 + lk * 8;
#pragma unroll
      for (int tm = 0; tm < 4; ++tm)
        af[tm] = __builtin_bit_cast(f16x8, *reinterpret_cast<const uint4*>(
                     A + (tm * 16 + lm) * 256 + ko));
#pragma unroll
      for (int tn = 0; tn < 4; ++tn)
        bf[tn] = __builtin_bit_cast(f16x8, *reinterpret_cast<const uint4*>(
                     B + (tn * 16 + lm) * 256 + ko));
#pragma unroll
      for (int tm = 0; tm < 4; ++tm)
#pragma unroll
        for (int tn = 0; tn < 4; ++tn)
          acc[tm][tn] = __builtin_amdgcn_mfma_f32_16x16x32_f16(
              af[tm], bf[tn], acc[tm][tn], 0, 0, 0);
    }
#pragma unroll
    for (int tm = 0; tm < 4; ++tm)
#pragma unroll
      for (int tn = 0; tn < 4; ++tn)
#pragma unroll
        for (int r = 0; r < 4; ++r)
          c_lds[tm * 16 + lk * 4 + r][tn * 16 + lm] = acc[tm][tn][r];
    LDS_FENCE();
  }

#pragma unroll
  for (int dI = 0; dI < 6; ++dI) {
    int d = dils[dI];
    if (o % d) continue;
    int ud = o / d;
    if (ud < -4 || ud > 4) continue;
    long ob = (long)b * 1741824 + (long)(1 + dI) * 248832 +
              (long)(ud + 4) * 27648 + (long)i * 64 + l;
#pragma unroll
    for (int v = 0; v < 9; ++v) {
      float val = 0.f;
      if (valid) {
        int j2 = l + (v - 4) * d;
        val = (j2 >= 0 && j2 < 64) ? c_lds[l][j2] : 0.f;
      }
      out[ob + (long)v * 3072] = val;
    }
  }
}

// ---------------------------------------------------------------------------
// Fallback level-1 (round-6 passing kernel) for small ws_size.
// ---------------------------------------------------------------------------
__global__ __launch_bounds__(64) void corr1_kernel(
    const float* __restrict__ x1, const float* __restrict__ x2,
    const float* __restrict__ ws, float* __restrict__ out) {
  int bx = blockIdx.x;
  int L = (bx & 7) * 1296 + (bx >> 3);
  int u = L % 9, dI = (L / 9) % 6, i = (L / 54) % 48, b = L / 2592;
  const int dils[6] = {1, 2, 3, 5, 9, 16};
  int d = dils[dI];
  int y = i + (u - 4) * d;
  int lane = threadIdx.x;
  long ob = (long)b * 1741824 + (long)(1 + dI) * 248832 + (long)u * 27648 +
            (long)i * 64 + lane;
  if (y < 0 || y >= 48) {
#pragma unroll
    for (int v = 0; v < 9; ++v) out[ob + v * 3072] = 0.f;
    return;
  }
  __shared__ uint4 x2t[192];
  x2t[lane] = make_uint4(0, 0, 0, 0);
  x2t[lane + 64] = make_uint4(0, 0, 0, 0);
  x2t[lane + 128] = make_uint4(0, 0, 0, 0);
  float acc[9];
#pragma unroll
  for (int v = 0; v < 9; ++v) acc[v] = 0.f;
  const float* x2row = x2 + (long)b * 786432 + (long)y * 64 + lane;
  const float* x1row = x1 + (long)b * 786432 + (long)i * 64 + lane;
#pragma unroll 1
  for (int cc8 = 0; cc8 < 32; ++cc8) {
    float x1v[8]; uint32_t xb[8];
#pragma unroll
    for (int cc = 0; cc < 8; ++cc) {
      long c = cc8 * 8 + cc;
      xb[cc] = __float_as_uint(x2row[c * 3072]) + 0x8000u;
      x1v[cc] = x1row[c * 3072];
    }
    uint4 pk;
    pk.x = (xb[0] >> 16) | (xb[1] & 0xffff0000u);
    pk.y = (xb[2] >> 16) | (xb[3] & 0xffff0000u);
    pk.z = (xb[4] >> 16) | (xb[5] & 0xffff0000u);
    pk.w = (xb[6] >> 16) | (xb[7] & 0xffff0000u);
    x2t[64 + lane] = pk;
    LDS_FENCE();
#pragma unroll
    for (int v = 0; v < 9; ++v) {
      uint4 q = x2t[64 + lane + (v - 4) * d];
      float s;
      s  = x1v[0] * __uint_as_float(q.x << 16);
      s += x1v[1] * __uint_as_float(q.x & 0xffff0000u);
      s += x1v[2] * __uint_as_float(q.y << 16);
      s += x1v[3] * __uint_as_float(q.y & 0xffff0000u);
      s += x1v[4] * __uint_as_float(q.z << 16);
      s += x1v[5] * __uint_as_float(q.z & 0xffff0000u);
      s += x1v[6] * __uint_as_float(q.w << 16);
      s += x1v[7] * __uint_as_float(q.w & 0xffff0000u);
      acc[v] += s;
    }
    LDS_FENCE();
  }
  const float* i1 = ws + b * 3072 + i * 64;
  const float* i2 = ws + 12288 + b * 3072 + y * 64;
  float inv1 = i1[lane];
#pragma unroll
  for (int v = 0; v < 9; ++v) {
    int col = lane + (v - 4) * d;
    float i2v = (col >= 0 && col < 64) ? i2[col] : 0.f;
    out[ob + v * 3072] = acc[v] * inv1 * i2v;
  }
}

extern "C" void kernel_launch(void* const* d_in, const int* in_sizes, int n_in,
                              void* d_out, int out_size, void* d_ws, size_t ws_size,
                              hipStream_t stream) {
  const float* x1_0 = (const float*)d_in[0];
  const float* x1_1 = (const float*)d_in[1];
  const float* x2_0 = (const float*)d_in[2];
  const float* x2_1 = (const float*)d_in[3];
  float* out = (float*)d_out;
  float* ws = (float*)d_ws;
  corr0_kernel<<<768, 256, 0, stream>>>(x1_0, x2_0, out);
  zfill0_kernel<<<45, 256, 0, stream>>>(out);
  if (ws_size >= 12681216) {
    __fp16* w1h = (__fp16*)((char*)d_ws + 98304);
    __fp16* w2h = w1h + 3145728;              // 4*48*64*256 elems
    xpose1_kernel<<<384, 256, 0, stream>>>(x1_1, x2_1, w1h, w2h);
    corr1m_kernel<<<7488, 64, 0, stream>>>(w1h, w2h, out);
  } else {
    norms1_kernel<<<96, 256, 0, stream>>>(x1_1, x2_1, ws);
    corr1_kernel<<<10368, 64, 0, stream>>>(x1_1, x2_1, ws, out);
  }
}

// Round 12
// 128.369 us; speedup vs baseline: 1.0939x; 1.0479x over previous
//
#include <hip/hip_runtime.h>
#include <stdint.h>

#define EPSN 1e-9f

typedef __fp16 f16x8 __attribute__((ext_vector_type(8)));
typedef float f32x4 __attribute__((ext_vector_type(4)));

// Wave-level LDS fence (rule #18: sched_barrier after waitcnt).
#define LDS_FENCE()                                        \
  do {                                                     \
    asm volatile("s_waitcnt lgkmcnt(0)" ::: "memory");     \
    __builtin_amdgcn_sched_barrier(0);                     \
  } while (0)

// ---------------------------------------------------------------------------
// ws layout: [0) inv1_1 [4][3072] f32  [12288) inv2_1 [4][3072] f32
//            byte 98304: w1h [4][48][64][256] f16 (6291456 B)
//            byte 6389760: w2h same                (6291456 B)
// fast path needs 12681216 B total.
// ---------------------------------------------------------------------------

__global__ __launch_bounds__(256) void norms1_kernel(
    const float* __restrict__ x1_1, const float* __restrict__ x2_1,
    float* __restrict__ ws) {
  int p = blockIdx.x * 256 + threadIdx.x;     // 24576 total
  const float* src = (p < 12288) ? x1_1 : x2_1;
  int q = (p < 12288) ? p : p - 12288;        // 12288 is NOT pow2
  long base = (long)(q / 3072) * 786432 + (q % 3072);
  float ss = 0.f;
#pragma unroll 8
  for (int c = 0; c < 256; ++c) { float v = src[base + (long)c * 3072]; ss += v * v; }
  ws[p] = 1.f / (sqrtf(ss) + EPSN);
}

// ---------------------------------------------------------------------------
// Level 0 (round-6 PROVEN version, ~63-66us): block per (b,i,u), 1728 blocks,
// XCD-swizzled, fused norms, shuffle-based inner loop, OOB u -> zero-writes.
// Restored after rounds 8-11 showed the (b,y) 768-block regrid was a 2x
// occupancy/latency regression (27 -> 12 waves/CU).
// ---------------------------------------------------------------------------
__global__ __launch_bounds__(256) void corr0_kernel(
    const float* __restrict__ x1, const float* __restrict__ x2,
    float* __restrict__ out) {
  int bx = blockIdx.x;
  int L = (bx & 7) * 216 + (bx >> 3);         // 1728 = 8 * 216 (bijective)
  int u = L % 9, i = (L / 9) % 48, b = L / 432;
  int y = 4 * i + u - 4;
  int tid = threadIdx.x;
  long ob = (long)b * 1741824 + (long)u * 27648 + (long)i * 64;
  if (y < 0 || y >= 192) {
    for (int idx = tid; idx < 576; idx += 256)
      out[ob + (idx >> 6) * 3072 + (idx & 63)] = 0.f;
    return;
  }
  __shared__ float red[4][14][64];
  __shared__ float inv2s[264];                 // pads [0..3],[260..263] = 0
  __shared__ float inv1s[64];
  int w = tid >> 6, lane = tid & 63;
  float acc4 = 0.f, acc5 = 0.f, acc6 = 0.f, acc7 = 0.f;
  float aL0 = 0.f, aL1 = 0.f, aL2 = 0.f, aL3 = 0.f, a8 = 0.f;
  float sq0 = 0.f, sq1 = 0.f, sq2 = 0.f, sq3 = 0.f, s1 = 0.f;
  const float* x2row = x2 + (long)b * 12582912 + (long)y * 256 + 4 * lane;
  const float* x1p   = x1 + (long)b * 12582912 + (long)(4 * i) * 256 + 4 * lane;
#pragma unroll 8
  for (int cc = 0; cc < 64; ++cc) {
    long off = (long)(w * 64 + cc) * 49152;
    float4 f = *reinterpret_cast<const float4*>(x2row + off);
    float xv = x1p[off];
    float xr = __shfl_down(xv, 1);            // x1 of lane j+1
    float xl = __shfl_up(xv, 1);              // x1 of lane j-1
    sq0 += f.x * f.x; sq1 += f.y * f.y; sq2 += f.z * f.z; sq3 += f.w * f.w;
    s1  += xv * xv;
    aL0 += xr * f.x; aL1 += xr * f.y; aL2 += xr * f.z; aL3 += xr * f.w;
    acc4 += xv * f.x; acc5 += xv * f.y; acc6 += xv * f.z; acc7 += xv * f.w;
    a8  += xl * f.x;
  }
  // realign: acc[v<4](j) lives at lane j-1; acc[8](j) lives at lane j+1.
  float o0 = __shfl_up(aL0, 1), o1 = __shfl_up(aL1, 1);
  float o2 = __shfl_up(aL2, 1), o3 = __shfl_up(aL3, 1);
  float o8 = __shfl_down(a8, 1);
  // (lane-0 / lane-63 stale values map to OOB cols -> zeroed by inv2s pads)
  red[w][0][lane] = o0;   red[w][1][lane] = o1;   red[w][2][lane] = o2;
  red[w][3][lane] = o3;   red[w][4][lane] = acc4; red[w][5][lane] = acc5;
  red[w][6][lane] = acc6; red[w][7][lane] = acc7; red[w][8][lane] = o8;
  red[w][9][lane] = sq0;  red[w][10][lane] = sq1; red[w][11][lane] = sq2;
  red[w][12][lane] = sq3; red[w][13][lane] = s1;
  __syncthreads();
  {
    int comp = tid & 3, jj = tid >> 2;        // col = tid (0..255)
    float ss = red[0][9 + comp][jj] + red[1][9 + comp][jj] +
               red[2][9 + comp][jj] + red[3][9 + comp][jj];
    inv2s[4 + tid] = 1.f / (sqrtf(ss) + EPSN);
    if (tid < 4) { inv2s[tid] = 0.f; inv2s[260 + tid] = 0.f; }
    if (tid < 64) {
      float t = red[0][13][tid] + red[1][13][tid] +
                red[2][13][tid] + red[3][13][tid];
      inv1s[tid] = 1.f / (sqrtf(t) + EPSN);
    }
  }
  __syncthreads();
  for (int idx = tid; idx < 576; idx += 256) {
    int v = idx >> 6, j = idx & 63;
    float s = red[0][v][j] + red[1][v][j] + red[2][v][j] + red[3][v][j];
    out[ob + v * 3072 + j] = s * inv1s[j] * inv2s[4 * j + v];  // col=4j+v-4
  }
}

// ---------------------------------------------------------------------------
// Normalize + f16 + transpose level-1 tensors into ws (unchanged, passing).
// ---------------------------------------------------------------------------
__global__ __launch_bounds__(256) void xpose1_kernel(
    const float* __restrict__ x1, const float* __restrict__ x2,
    __fp16* __restrict__ o1, __fp16* __restrict__ o2) {
  int bx = blockIdx.x;                        // 384 = 2 * 4 * 48
  int tz = bx & 1; int rem = bx >> 1;
  int i = rem % 48, b = rem / 48;
  const float* src = tz ? x2 : x1;
  __fp16* dst = (tz ? o2 : o1) + (long)(b * 48 + i) * 16384;  // 64*256
  __shared__ uint32_t lds[64 * 128];          // 64 rows x 512 B
  __shared__ float sred[4][64];
  int t = threadIdx.x;
  int j = t & 63, cg = t >> 6;                // wave = cg
  const float* sp = src + (long)b * 786432 + (long)i * 64 + j;
  float ss = 0.f;
#pragma unroll 8
  for (int c8 = 0; c8 < 64; ++c8) {
    float v = sp[(long)(cg * 64 + c8) * 3072];
    ss += v * v;
  }
  sred[cg][j] = ss;
  __syncthreads();
  float invv = 1.f / (sqrtf(sred[0][j] + sred[1][j] + sred[2][j] + sred[3][j]) + EPSN);
#pragma unroll
  for (int cb = 0; cb < 8; ++cb) {
    uint32_t pk[4];
#pragma unroll
    for (int e2 = 0; e2 < 4; ++e2) {
      int c0 = cg * 64 + cb * 8 + e2 * 2;
      __fp16 h0 = (__fp16)(sp[(long)c0 * 3072] * invv);
      __fp16 h1 = (__fp16)(sp[(long)(c0 + 1) * 3072] * invv);
      pk[e2] = (uint32_t)__builtin_bit_cast(uint16_t, h0) |
               ((uint32_t)__builtin_bit_cast(uint16_t, h1) << 16);
    }
    int byteoff = j * 512 + ((cg * 128 + cb * 16) ^ ((j & 7) << 4));
    *reinterpret_cast<uint4*>(reinterpret_cast<char*>(lds) + byteoff) =
        make_uint4(pk[0], pk[1], pk[2], pk[3]);
  }
  __syncthreads();
#pragma unroll
  for (int rep = 0; rep < 8; ++rep) {
    int idx = rep * 256 + t;
    int jj = idx >> 5, cb = idx & 31;
    int byteoff = jj * 512 + ((cb * 16) ^ ((jj & 7) << 4));
    uint4 val = *reinterpret_cast<const uint4*>(
        reinterpret_cast<const char*>(lds) + byteoff);
    *reinterpret_cast<uint4*>(reinterpret_cast<char*>(dst) + jj * 512 + cb * 16) = val;
  }
}

// ---------------------------------------------------------------------------
// Level 1 via MFMA, zfill merged (unchanged, passing).
// ---------------------------------------------------------------------------
__device__ const int OFFS39[39] = {
    0, 1, -1, 2, -2, 3, -3, 4, -4, 5, -5, 6, -6, 8, -8, 9, -9, 10, -10,
    12, -12, 15, -15, 16, -16, 18, -18, 20, -20, 27, -27, 32, -32, 36, -36,
    48, -48, 64, -64};

__global__ __launch_bounds__(64) void corr1m_kernel(
    const __fp16* __restrict__ w1, const __fp16* __restrict__ w2,
    float* __restrict__ out) {
  const int dils[6] = {1, 2, 3, 5, 9, 16};
  int bx = blockIdx.x;
  int L = (bx & 7) * 936 + (bx >> 3);         // 7488 = 8 * 936 (bijective)
  int oi = L % 39, i = (L / 39) % 48, b = L / 1872;
  int o = OFFS39[oi];
  int y = i + o;
  bool valid = (y >= 0 && y < 48);
  int l = threadIdx.x;
  __shared__ float c_lds[64][65];

  if (valid) {
    int lm = l & 15, lk = l >> 4;
    const __fp16* A = w1 + (long)(b * 48 + i) * 16384;   // [j1][c]
    const __fp16* B = w2 + (long)(b * 48 + y) * 16384;   // [j2][c]
    f32x4 acc[4][4];
#pragma unroll
    for (int tm = 0; tm < 4; ++tm)
#pragma unroll
      for (int tn = 0; tn < 4; ++tn) acc[tm][tn] = (f32x4)0.f;

    for (int ks = 0; ks < 8; ++ks) {
      f16x8 af[4], bf[4];
      int ko = ks * 32 + lk * 8;
#pragma unroll
      for (int tm = 0; tm < 4; ++tm)
        af[tm] = __builtin_bit_cast(f16x8, *reinterpret_cast<const uint4*>(
                     A + (tm * 16 + lm) * 256 + ko));
#pragma unroll
      for (int tn = 0; tn < 4; ++tn)
        bf[tn] = __builtin_bit_cast(f16x8, *reinterpret_cast<const uint4*>(
                     B + (tn * 16 + lm) * 256 + ko));
#pragma unroll
      for (int tm = 0; tm < 4; ++tm)
#pragma unroll
        for (int tn = 0; tn < 4; ++tn)
          acc[tm][tn] = __builtin_amdgcn_mfma_f32_16x16x32_f16(
              af[tm], bf[tn], acc[tm][tn], 0, 0, 0);
    }
#pragma unroll
    for (int tm = 0; tm < 4; ++tm)
#pragma unroll
      for (int tn = 0; tn < 4; ++tn)
#pragma unroll
        for (int r = 0; r < 4; ++r)
          c_lds[tm * 16 + lk * 4 + r][tn * 16 + lm] = acc[tm][tn][r];
    LDS_FENCE();
  }

#pragma unroll
  for (int dI = 0; dI < 6; ++dI) {
    int d = dils[dI];
    if (o % d) continue;
    int ud = o / d;
    if (ud < -4 || ud > 4) continue;
    long ob = (long)b * 1741824 + (long)(1 + dI) * 248832 +
              (long)(ud + 4) * 27648 + (long)i * 64 + l;
#pragma unroll
    for (int v = 0; v < 9; ++v) {
      float val = 0.f;
      if (valid) {
        int j2 = l + (v - 4) * d;
        val = (j2 >= 0 && j2 < 64) ? c_lds[l][j2] : 0.f;
      }
      out[ob + (long)v * 3072] = val;
    }
  }
}

// ---------------------------------------------------------------------------
// Fallback level-1 (round-6 passing kernel) for small ws_size.
// ---------------------------------------------------------------------------
__global__ __launch_bounds__(64) void corr1_kernel(
    const float* __restrict__ x1, const float* __restrict__ x2,
    const float* __restrict__ ws, float* __restrict__ out) {
  int bx = blockIdx.x;
  int L = (bx & 7) * 1296 + (bx >> 3);
  int u = L % 9, dI = (L / 9) % 6, i = (L / 54) % 48, b = L / 2592;
  const int dils[6] = {1, 2, 3, 5, 9, 16};
  int d = dils[dI];
  int y = i + (u - 4) * d;
  int lane = threadIdx.x;
  long ob = (long)b * 1741824 + (long)(1 + dI) * 248832 + (long)u * 27648 +
            (long)i * 64 + lane;
  if (y < 0 || y >= 48) {
#pragma unroll
    for (int v = 0; v < 9; ++v) out[ob + v * 3072] = 0.f;
    return;
  }
  __shared__ uint4 x2t[192];
  x2t[lane] = make_uint4(0, 0, 0, 0);
  x2t[lane + 64] = make_uint4(0, 0, 0, 0);
  x2t[lane + 128] = make_uint4(0, 0, 0, 0);
  float acc[9];
#pragma unroll
  for (int v = 0; v < 9; ++v) acc[v] = 0.f;
  const float* x2row = x2 + (long)b * 786432 + (long)y * 64 + lane;
  const float* x1row = x1 + (long)b * 786432 + (long)i * 64 + lane;
#pragma unroll 1
  for (int cc8 = 0; cc8 < 32; ++cc8) {
    float x1v[8]; uint32_t xb[8];
#pragma unroll
    for (int cc = 0; cc < 8; ++cc) {
      long c = cc8 * 8 + cc;
      xb[cc] = __float_as_uint(x2row[c * 3072]) + 0x8000u;
      x1v[cc] = x1row[c * 3072];
    }
    uint4 pk;
    pk.x = (xb[0] >> 16) | (xb[1] & 0xffff0000u);
    pk.y = (xb[2] >> 16) | (xb[3] & 0xffff0000u);
    pk.z = (xb[4] >> 16) | (xb[5] & 0xffff0000u);
    pk.w = (xb[6] >> 16) | (xb[7] & 0xffff0000u);
    x2t[64 + lane] = pk;
    LDS_FENCE();
#pragma unroll
    for (int v = 0; v < 9; ++v) {
      uint4 q = x2t[64 + lane + (v - 4) * d];
      float s;
      s  = x1v[0] * __uint_as_float(q.x << 16);
      s += x1v[1] * __uint_as_float(q.x & 0xffff0000u);
      s += x1v[2] * __uint_as_float(q.y << 16);
      s += x1v[3] * __uint_as_float(q.y & 0xffff0000u);
      s += x1v[4] * __uint_as_float(q.z << 16);
      s += x1v[5] * __uint_as_float(q.z & 0xffff0000u);
      s += x1v[6] * __uint_as_float(q.w << 16);
      s += x1v[7] * __uint_as_float(q.w & 0xffff0000u);
      acc[v] += s;
    }
    LDS_FENCE();
  }
  const float* i1 = ws + b * 3072 + i * 64;
  const float* i2 = ws + 12288 + b * 3072 + y * 64;
  float inv1 = i1[lane];
#pragma unroll
  for (int v = 0; v < 9; ++v) {
    int col = lane + (v - 4) * d;
    float i2v = (col >= 0 && col < 64) ? i2[col] : 0.f;
    out[ob + v * 3072] = acc[v] * inv1 * i2v;
  }
}

extern "C" void kernel_launch(void* const* d_in, const int* in_sizes, int n_in,
                              void* d_out, int out_size, void* d_ws, size_t ws_size,
                              hipStream_t stream) {
  const float* x1_0 = (const float*)d_in[0];
  const float* x1_1 = (const float*)d_in[1];
  const float* x2_0 = (const float*)d_in[2];
  const float* x2_1 = (const float*)d_in[3];
  float* out = (float*)d_out;
  float* ws = (float*)d_ws;
  corr0_kernel<<<1728, 256, 0, stream>>>(x1_0, x2_0, out);
  if (ws_size >= 12681216) {
    __fp16* w1h = (__fp16*)((char*)d_ws + 98304);
    __fp16* w2h = w1h + 3145728;              // 4*48*64*256 elems
    xpose1_kernel<<<384, 256, 0, stream>>>(x1_1, x2_1, w1h, w2h);
    corr1m_kernel<<<7488, 64, 0, stream>>>(w1h, w2h, out);
  } else {
    norms1_kernel<<<96, 256, 0, stream>>>(x1_1, x2_1, ws);
    corr1_kernel<<<10368, 64, 0, stream>>>(x1_1, x2_1, ws, out);
  }
}